// Round 1
// baseline (156.567 us; speedup 1.0000x reference)
//
#include <hip/hip_runtime.h>

// Problem: B=64, ZD=E=512, L=8192, NL=1000, all fp32.
// out[b,l] = s[b] * dot(zz[b,:], W_zlat[l,:])
//   zz = irm(z, Wz1/bz1, Wz2/bz2)
//   s[b] = dot(irm(ye0, Wy1/by1, Wy2/by2)[b,:], w_proj),  ye0[b,e] = W_yemb[e, y[b]] + b_yemb[e]

#define BB 64
#define DD 512
#define LL 8192
#define NLBL 1000

#define KC 64        // k-chunk staged in LDS
#define PITCH 68     // LDS row pitch (floats), pad to de-phase banks, 16B-aligned rows

// ---------------- K0: gather one-hot embedding column + zero s ----------------
__global__ __launch_bounds__(256) void gather_kernel(
    const float* __restrict__ W_yemb, const float* __restrict__ b_yemb,
    const int* __restrict__ y, float* __restrict__ ye0, float* __restrict__ s) {
  int b = blockIdx.x;
  int yb = y[b];
  const float* col = W_yemb + yb;                 // column y[b], stride NLBL
  for (int e = threadIdx.x; e < DD; e += 256)
    ye0[b * DD + e] = col[(size_t)e * NLBL] + b_yemb[e];
  if (b == 0 && threadIdx.x < BB) s[threadIdx.x] = 0.f;
}

// ---------------- K1/K2: one residual-linear layer for BOTH paths ------------
// out[b,j] = X[b,j] + bias[j] + dot(X[b,:], W[j,:])
// grid = 128 blocks: blocks 0..63 z-path (j-tile of 8), 64..127 e-path.
// If s_accum != null, e-path skips the store and accumulates dot(ye2, w_proj).
#define JT 8
__global__ __launch_bounds__(256) void layer_kernel(
    const float* __restrict__ Xz, const float* __restrict__ Wz,
    const float* __restrict__ bz, float* __restrict__ Oz,
    const float* __restrict__ Xe, const float* __restrict__ We,
    const float* __restrict__ be, float* __restrict__ Oe,
    const float* __restrict__ w_proj, float* __restrict__ s_accum) {
  __shared__ __align__(16) float Wl[JT * PITCH];
  __shared__ __align__(16) float Xl[BB * PITCH];
  int tid = threadIdx.x;
  int isE = blockIdx.x >> 6;
  int jt0 = (blockIdx.x & 63) * JT;
  const float* X = isE ? Xe : Xz;
  const float* W = isE ? We : Wz;
  const float* bias = isE ? be : bz;

  int jl = tid & 7;          // j within tile
  int j = jt0 + jl;
  int bg = tid >> 3;         // 0..31, two batches each
  int b0 = bg * 2;
  float acc0 = 0.f, acc1 = 0.f;

  for (int kc = 0; kc < DD; kc += KC) {
    // stage W tile: JT x KC = 512 floats = 128 float4 (threads 0..127)
    if (tid < 128) {
      int row = tid >> 4, c4 = tid & 15;
      *(float4*)&Wl[row * PITCH + c4 * 4] =
          *(const float4*)&W[(jt0 + row) * DD + kc + c4 * 4];
    }
    // stage X chunk: BB x KC = 4096 floats = 1024 float4, 4 per thread
#pragma unroll
    for (int i = 0; i < 4; ++i) {
      int slot = tid + i * 256;
      int row = slot >> 4, c4 = slot & 15;
      *(float4*)&Xl[row * PITCH + c4 * 4] =
          *(const float4*)&X[row * DD + kc + c4 * 4];
    }
    __syncthreads();
#pragma unroll
    for (int k = 0; k < KC; k += 4) {
      float4 w  = *(const float4*)&Wl[jl * PITCH + k];
      float4 x0 = *(const float4*)&Xl[b0 * PITCH + k];
      float4 x1 = *(const float4*)&Xl[(b0 + 1) * PITCH + k];
      acc0 += w.x * x0.x + w.y * x0.y + w.z * x0.z + w.w * x0.w;
      acc1 += w.x * x1.x + w.y * x1.y + w.z * x1.z + w.w * x1.w;
    }
    __syncthreads();
  }

  float r0 = X[b0 * DD + j] + bias[j] + acc0;
  float r1 = X[(b0 + 1) * DD + j] + bias[j] + acc1;

  if (s_accum && isE) {
    // fold s[b] = dot(ye2[b,:], w_proj) — reduce over the 8 j-lanes
    float wp = w_proj[j];
    float v0 = r0 * wp, v1 = r1 * wp;
#pragma unroll
    for (int d = 4; d > 0; d >>= 1) {
      v0 += __shfl_down(v0, d, 8);
      v1 += __shfl_down(v1, d, 8);
    }
    if (jl == 0) {
      atomicAdd(&s_accum[b0], v0);
      atomicAdd(&s_accum[b0 + 1], v1);
    }
  } else {
    float* O = isE ? Oe : Oz;
    O[b0 * DD + j] = r0;
    O[(b0 + 1) * DD + j] = r1;
  }
}

// ---------------- K3: out[b,l] = s[b] * dot(zz[b,:], W_zlat[l,:]) -------------
// grid = 256 blocks, each owns 32 consecutive l-rows x all 64 batches.
#define LT 32
__global__ __launch_bounds__(256) void out_kernel(
    const float* __restrict__ zz, const float* __restrict__ Wz_lat,
    const float* __restrict__ s, float* __restrict__ out) {
  __shared__ __align__(16) float Wt[LT * PITCH];
  __shared__ __align__(16) float Xt[BB * PITCH];
  int tid = threadIdx.x;
  int l0 = blockIdx.x * LT;
  int lt = tid & 31;
  int bg = tid >> 5;         // 0..7, eight batches each
  float acc[8] = {0.f, 0.f, 0.f, 0.f, 0.f, 0.f, 0.f, 0.f};

  for (int kc = 0; kc < DD; kc += KC) {
    // stage W tile: LT x KC = 2048 floats = 512 float4, 2 per thread
#pragma unroll
    for (int i = 0; i < 2; ++i) {
      int slot = tid + i * 256;
      int row = slot >> 4, c4 = slot & 15;
      *(float4*)&Wt[row * PITCH + c4 * 4] =
          *(const float4*)&Wz_lat[(size_t)(l0 + row) * DD + kc + c4 * 4];
    }
    // stage zz chunk: BB x KC = 1024 float4, 4 per thread (L2-broadcast)
#pragma unroll
    for (int i = 0; i < 4; ++i) {
      int slot = tid + i * 256;
      int row = slot >> 4, c4 = slot & 15;
      *(float4*)&Xt[row * PITCH + c4 * 4] =
          *(const float4*)&zz[row * DD + kc + c4 * 4];
    }
    __syncthreads();
#pragma unroll
    for (int k = 0; k < KC; k += 4) {
      float4 w = *(const float4*)&Wt[lt * PITCH + k];
#pragma unroll
      for (int i = 0; i < 8; ++i) {
        float4 x = *(const float4*)&Xt[(bg * 8 + i) * PITCH + k];
        acc[i] += w.x * x.x + w.y * x.y + w.z * x.z + w.w * x.w;
      }
    }
    __syncthreads();
  }

  int l = l0 + lt;
#pragma unroll
  for (int i = 0; i < 8; ++i) {
    int b = bg * 8 + i;
    out[(size_t)b * LL + l] = s[b] * acc[i];   // coalesced: lanes -> consecutive l
  }
}

extern "C" void kernel_launch(void* const* d_in, const int* in_sizes, int n_in,
                              void* d_out, int out_size, void* d_ws, size_t ws_size,
                              hipStream_t stream) {
  const float* z      = (const float*)d_in[0];
  const int*   y      = (const int*)  d_in[1];
  const float* W_yemb = (const float*)d_in[2];
  const float* b_yemb = (const float*)d_in[3];
  const float* Wy1    = (const float*)d_in[4];
  const float* by1    = (const float*)d_in[5];
  const float* Wy2    = (const float*)d_in[6];
  const float* by2    = (const float*)d_in[7];
  const float* Wz1    = (const float*)d_in[8];
  const float* bz1    = (const float*)d_in[9];
  const float* Wz2    = (const float*)d_in[10];
  const float* bz2    = (const float*)d_in[11];
  const float* W_zlat = (const float*)d_in[12];
  const float* w_proj = (const float*)d_in[13];

  float* ws  = (float*)d_ws;
  float* x1z = ws;            // [64*512]
  float* x1e = ws + 32768;    // [64*512]
  float* zz  = ws + 65536;    // [64*512]
  float* ye0 = ws + 98304;    // [64*512]
  float* sb  = ws + 131072;   // [64]
  float* out = (float*)d_out;

  gather_kernel<<<64, 256, 0, stream>>>(W_yemb, b_yemb, y, ye0, sb);
  layer_kernel<<<128, 256, 0, stream>>>(z,   Wz1, bz1, x1z, ye0, Wy1, by1, x1e,
                                        nullptr, nullptr);
  layer_kernel<<<128, 256, 0, stream>>>(x1z, Wz2, bz2, zz,  x1e, Wy2, by2, nullptr,
                                        w_proj, sb);
  out_kernel<<<256, 256, 0, stream>>>(zz, W_zlat, sb, out);
}